// Round 5
// baseline (49.078 us; speedup 1.0000x reference)
//
#include <hip/hip_runtime.h>

#define KOBJ  128
#define QMIN  0.5f
#define SB    1.0f
#define BDIM  256
#define NSCB  128           // scan blocks per batch element
#define BATCH 8
#define PPB   256           // points per pairs-block (1 per thread)

// ---- workspace layout (bytes); NO zero-init required ----
// 0       : u64  pkey [BATCH*NSCB][KOBJ]  1048576 B
// 1048576 : f32  nsp  [BATCH*NSCB]           4096 B
// 1052672 : u32  ncp  [BATCH*NSCB]           4096 B
// 1056768 : f4   xaq  [BATCH][KOBJ]         16384 B  {x_a, y_a, q_a*present, 0}
// 1073152 : f32  terms[BATCH]                  32 B  L_beta + L_noise
// 1073184 : f32  qsum [BATCH]                  32 B  sum of q_a*present
// 1073216 : f32  pairp[BATCH*157]            5024 B
// 1078240 : u32  ctr                             4 B  (zeroed by oc_scan each call)

__device__ __forceinline__ float waveRedF(float v) {
    #pragma unroll
    for (int o = 32; o; o >>= 1) v += __shfl_down(v, o, 64);
    return v;
}
__device__ __forceinline__ unsigned int waveRedU(unsigned int v) {
    #pragma unroll
    for (int o = 32; o; o >>= 1) v += __shfl_down(v, o, 64);
    return v;
}
__device__ __forceinline__ float agentLoadF(const float* p) {
    return __hip_atomic_load(p, __ATOMIC_RELAXED, __HIP_MEMORY_SCOPE_AGENT);
}

__global__ void __launch_bounds__(BDIM)
oc_scan(const float* __restrict__ beta, const int* __restrict__ t_idx,
        unsigned long long* __restrict__ pkey,
        float* __restrict__ nsp, unsigned int* __restrict__ ncp,
        unsigned int* __restrict__ ctr, int N) {
    const int tid = threadIdx.x;
    const int b   = blockIdx.y;
    const int sub = blockIdx.x;
    const int bid = b * NSCB + sub;
    const int chunk = (N + NSCB - 1) / NSCB;
    const int n0 = sub * chunk;
    const int n1 = min(n0 + chunk, N);

    if (sub == 0 && b == 0 && tid == 0) ctr[0] = 0u;   // reset last-block counter

    __shared__ unsigned long long skey[KOBJ];
    if (tid < KOBJ) skey[tid] = 0ull;
    __syncthreads();

    float ns = 0.f;
    unsigned int nc = 0u;
    for (int n = n0 + tid; n < n1; n += BDIM) {
        const float bc = fminf(fmaxf(beta[(size_t)b * N + n], 1e-6f), 1.0f - 1e-5f);
        const int t = t_idx[(size_t)b * N + n];
        const unsigned long long kk =
            ((unsigned long long)__float_as_uint(bc) << 32) |
            (unsigned long long)(~(unsigned int)n);          // ties -> smallest n
        atomicMax(&skey[t], kk);                              // LDS atomic
        if (t == 0) { ns += bc; nc++; }
    }
    __syncthreads();
    if (tid < KOBJ) pkey[(size_t)bid * KOBJ + tid] = skey[tid];

    ns = waveRedF(ns);
    nc = waveRedU(nc);
    __shared__ float s_ns[4];
    __shared__ unsigned int s_nc[4];
    if ((tid & 63) == 0) { s_ns[tid >> 6] = ns; s_nc[tid >> 6] = nc; }
    __syncthreads();
    if (tid == 0) {
        float a = 0.f; unsigned int c = 0u;
        #pragma unroll
        for (int w = 0; w < BDIM / 64; ++w) { a += s_ns[w]; c += s_nc[w]; }
        nsp[bid] = a; ncp[bid] = c;
    }
}

__global__ void __launch_bounds__(KOBJ)
oc_reduce(const float* __restrict__ cc,
          const unsigned long long* __restrict__ pkey,
          const float* __restrict__ nsp, const unsigned int* __restrict__ ncp,
          float4* __restrict__ xaq, float* __restrict__ terms,
          float* __restrict__ qsum, int N) {
    const int b = blockIdx.x;
    const int k = threadIdx.x;          // 128 threads

    unsigned long long kv = 0ull;
    #pragma unroll 8
    for (int s = 0; s < NSCB; ++s) {
        const unsigned long long v = pkey[(size_t)(b * NSCB + s) * KOBJ + k];
        kv = v > kv ? v : kv;
    }
    const bool present = (kv != 0ull) && (k > 0);
    float x = 0.f, y = 0.f, qv = 0.f, lb = 0.f;
    unsigned int pc = 0u;
    if (kv != 0ull) {
        const unsigned int na = ~(unsigned int)(kv & 0xFFFFFFFFull);
        const float ba = __uint_as_float((unsigned int)(kv >> 32));
        const float2 xy = *(const float2*)&cc[((size_t)b * N + na) * 2];
        x = xy.x; y = xy.y;
        const float a = atanhf(ba / 1.002f);
        qv = a * a + QMIN;
        if (present) { lb = 1.f - ba; pc = 1u; }
    }
    const float qe = present ? qv : 0.f;
    xaq[(size_t)b * KOBJ + k] = make_float4(x, y, qe, 0.f);

    // noise partials: one per thread (NSCB == KOBJ == 128)
    float ns = nsp[b * NSCB + k];
    unsigned int nc = ncp[b * NSCB + k];

    float qs = qe;
    lb = waveRedF(lb);  pc = waveRedU(pc);
    ns = waveRedF(ns);  nc = waveRedU(nc);
    qs = waveRedF(qs);
    __shared__ float s_lb[2], s_ns2[2], s_qs[2];
    __shared__ unsigned int s_pc[2], s_nc2[2];
    const int wv = k >> 6;
    if ((k & 63) == 0) { s_lb[wv] = lb; s_pc[wv] = pc; s_ns2[wv] = ns; s_nc2[wv] = nc; s_qs[wv] = qs; }
    __syncthreads();
    if (k == 0) {
        const float L = s_lb[0] + s_lb[1];
        const unsigned int P = s_pc[0] + s_pc[1];
        const float A = s_ns2[0] + s_ns2[1];
        const unsigned int C = s_nc2[0] + s_nc2[1];
        terms[b] = L / (float)max(P, 1u) + SB * A / (float)max(C, 1u);
        qsum[b]  = s_qs[0] + s_qs[1];
    }
}

__global__ void __launch_bounds__(PPB)
oc_pairs(const float* __restrict__ cc, const float* __restrict__ beta,
         const int* __restrict__ t_idx,
         const float4* __restrict__ xaq,
         const float* __restrict__ terms, const float* __restrict__ qsum,
         float* __restrict__ pairp, unsigned int* __restrict__ ctr,
         float* __restrict__ out, int N, int totalPB) {
    const int tid = threadIdx.x;
    const int b   = blockIdx.y;
    const int sub = blockIdx.x;
    const int bid = b * gridDim.x + sub;
    const int n   = sub * PPB + tid;

    __shared__ float4 stab[KOBJ];
    if (tid < KOBJ) stab[tid] = xaq[(size_t)b * KOBJ + tid];
    __syncthreads();

    float acc_tot = 0.f;
    if (n < N) {
        const float2 xy = *(const float2*)&cc[((size_t)b * N + n) * 2];
        const float bc = fminf(fmaxf(beta[(size_t)b * N + n], 1e-6f), 1.0f - 1e-5f);
        const int t = t_idx[(size_t)b * N + n];
        const float a = atanhf(bc / 1.002f);
        const float qn = a * a + QMIN;
        float acc = 0.f;                 // sum of q_k * min(d_k, 1)
        #pragma unroll 8
        for (int k = 0; k < KOBJ; ++k) {
            const float4 T = stab[k];
            const float dx = xy.x - T.x;
            const float dy = xy.y - T.y;
            const float m   = fmaf(dx, dx, 1e-6f);
            const float d2e = fmaf(dy, dy, m);
            const float d   = __builtin_amdgcn_sqrtf(d2e);
            acc = fmaf(T.z, fminf(d, 1.f), acc);
        }
        // repulsive total = qsum - acc; patch k==t: + q_t*(d2 - max(0,1-d))
        const float4 Tt = stab[t];
        const float dxt = xy.x - Tt.x;
        const float dyt = xy.y - Tt.y;
        const float mt   = fmaf(dxt, dxt, 1e-6f);
        const float d2et = fmaf(dyt, dyt, mt);
        const float dt   = __builtin_amdgcn_sqrtf(d2et);
        const float point = qsum[b] - acc
                          + Tt.z * ((d2et - 1e-6f) - 1.f + fminf(dt, 1.f));
        acc_tot = point * qn;
    }

    acc_tot = waveRedF(acc_tot);
    __shared__ float s_acc[PPB / 64];
    if ((tid & 63) == 0) s_acc[tid >> 6] = acc_tot;
    __syncthreads();

    __shared__ int amLast;
    if (tid == 0) {
        float s = 0.f;
        #pragma unroll
        for (int w = 0; w < PPB / 64; ++w) s += s_acc[w];
        pairp[bid] = s;
        __threadfence();
        const unsigned int old = atomicAdd(ctr, 1u);
        amLast = (old == (unsigned int)(totalPB - 1));
    }
    __syncthreads();

    if (amLast) {
        // deterministic final reduction (fixed-order trees, agent-scope loads)
        float p = 0.f;
        for (int i = tid; i < totalPB; i += PPB) p += agentLoadF(&pairp[i]);
        p = waveRedF(p);
        __shared__ float s_p[PPB / 64];
        if ((tid & 63) == 0) s_p[tid >> 6] = p;
        float t8 = (tid < BATCH) ? agentLoadF(&terms[tid]) : 0.f;
        t8 = waveRedF(t8);              // wave 0 lane 0 holds L
        __syncthreads();
        if (tid == 0) {
            float P = 0.f;
            #pragma unroll
            for (int w = 0; w < PPB / 64; ++w) P += s_p[w];
            out[0] = (P / (float)N + t8) / (float)BATCH;
        }
    }
}

extern "C" void kernel_launch(void* const* d_in, const int* in_sizes, int n_in,
                              void* d_out, int out_size, void* d_ws, size_t ws_size,
                              hipStream_t stream) {
    const float* cc   = (const float*)d_in[0];   // (B,N,2) f32
    const float* beta = (const float*)d_in[1];   // (B,N)   f32
    const int*   tid  = (const int*)d_in[2];     // (B,N)   i32
    float* out = (float*)d_out;
    const int N = in_sizes[1] / BATCH;

    char* ws = (char*)d_ws;
    unsigned long long* pkey = (unsigned long long*)(ws + 0);
    float*        nsp   = (float*)(ws + 1048576);
    unsigned int* ncp   = (unsigned int*)(ws + 1052672);
    float4*       xaq   = (float4*)(ws + 1056768);
    float*        terms = (float*)(ws + 1073152);
    float*        qsum  = (float*)(ws + 1073184);
    float*        pairp = (float*)(ws + 1073216);
    unsigned int* ctr   = (unsigned int*)(ws + 1078240);

    const int nppb = (N + PPB - 1) / PPB;        // pairs blocks per batch
    const int totalPB = nppb * BATCH;

    oc_scan  <<<dim3(NSCB, BATCH), BDIM, 0, stream>>>(beta, tid, pkey, nsp, ncp, ctr, N);
    oc_reduce<<<dim3(BATCH), KOBJ, 0, stream>>>(cc, pkey, nsp, ncp, xaq, terms, qsum, N);
    oc_pairs <<<dim3(nppb, BATCH), PPB, 0, stream>>>(cc, beta, tid, xaq, terms, qsum,
                                                     pairp, ctr, out, N, totalPB);
}